// Round 1
// baseline (178.168 us; speedup 1.0000x reference)
//
#include <hip/hip_runtime.h>
#include <math.h>

#define NPTS 2048
#define BATCH 16
#define KNN 16
#define HID 128
#define NPOINTS (BATCH * NPTS)   // 32768
#define RPB 8          // rows (queries) per block = waves per block
#define CAP 64         // compacted-candidate capacity per wave (m ~ 18.4 avg)

typedef __attribute__((ext_vector_type(8))) short bf16x8;
typedef __attribute__((ext_vector_type(4))) float f32x4;

__device__ inline unsigned short f2bf(float f) {    // RNE f32 -> bf16 bits
    unsigned u = __float_as_uint(f);
    return (unsigned short)((u + 0x7FFFu + ((u >> 16) & 1u)) >> 16);
}
__device__ inline float bflo(unsigned v) { return __uint_as_float(v << 16); }
__device__ inline float bfhi(unsigned v) { return __uint_as_float(v & 0xFFFF0000u); }

// Chunk-transposed bf16 layout: T[cc][point][8ch], cc = channel/8 (16 planes).
// Serves: contiguous 32KB/batch staging for the LDS gather, 256B-coalesced
// MFMA A-fragments (8 consecutive k == one chunk), coalesced epilogues.

// ---------------------------------------------------------------------------
// kNN + fused layer 1. One wave per query row.
// R10: selection phase moved off the LDS pipe. Threshold = rank-of-lane-min
// via 64x v_readlane (register-only, no serial ds_swizzle chain). Candidates
// compacted as packed u64 (key<<32|idx) -> one ds_write_b64; rank = one
// ds_read_b64 (own slot) + readlane loop (no dependent LDS broadcast chain).
// CAP 128->64 drops LDS to 38.9KB -> 4 blocks/CU (32 waves, 100% ceiling).
// ---------------------------------------------------------------------------
__global__ __launch_bounds__(512) void knn_kernel(
    const float* __restrict__ pc, int* __restrict__ nbr,
    const float* __restrict__ W1r, const float* __restrict__ b1,
    const float* __restrict__ W1s, unsigned short* __restrict__ x1T)
{
    __shared__ __align__(16) float4 pts[NPTS];              // 32 KB
    __shared__ unsigned long long cand[RPB][CAP];           // 4 KB
    __shared__ __align__(16) unsigned short xst[RPB][HID];  // 2 KB

    const int b = blockIdx.x >> 8;                    // 256 blocks per batch
    const int rblk = blockIdx.x & 255;
    const float* p = pc + (size_t)b * NPTS * 3;

    for (int t = threadIdx.x; t < NPTS; t += 512) {
        float x = p[t * 3 + 0], y = p[t * 3 + 1], z = p[t * 3 + 2];
        pts[t] = make_float4(x, y, z, x * x + y * y + z * z);
    }
    __syncthreads();

    const int w = threadIdx.x >> 6;
    const int lane = threadIdx.x & 63;
    const int i = rblk * RPB + w;                     // query row in batch
    const float4 pi = pts[i];
    const float piw16 = pi.w + 16.0f;

    unsigned key[32];
    unsigned km = 0xFFFFFFFFu;
    #pragma unroll
    for (int t = 0; t < 32; ++t) {
        float4 c = pts[t * 64 + lane];
        float dot = fmaf(pi.x, c.x, fmaf(pi.y, c.y, pi.z * c.z));
        float d2 = fmaf(-2.0f, dot, piw16 + c.w);     // = |pi-c|^2 + 16 > 0
        key[t] = __float_as_uint(d2);
        km = min(km, key[t]);
    }

    // ---- T0 = 16th-smallest of the 64 per-lane minima, register-only ------
    // rank of my km among all lane-mins (idx tie-break => unique rank 15)
    int rk = 0;
    #pragma unroll
    for (int j = 0; j < 64; ++j) {
        unsigned o = (unsigned)__builtin_amdgcn_readlane((int)km, j);
        rk += (o < km) || (o == km && j < lane);
    }
    unsigned long long sel15 = __ballot(rk == 15);
    const int srcl = __ffsll((long long)sel15) - 1;
    const unsigned T0 = (unsigned)__builtin_amdgcn_readlane((int)km, srcl);
    // >=16 candidates <= T0 and T0 >= true 16th => superset of the top-16.

    unsigned base = 0;
    #pragma unroll 1
    for (int t = 0; t < 32; ++t) {
        bool pred = key[t] <= T0;
        unsigned long long mask = __ballot(pred);
        if (mask) {
            unsigned prefix = __builtin_amdgcn_mbcnt_hi(
                (unsigned)(mask >> 32),
                __builtin_amdgcn_mbcnt_lo((unsigned)mask, 0));
            unsigned pos = base + prefix;
            if (pred && pos < CAP) {
                cand[w][pos] = ((unsigned long long)key[t] << 32)
                             | (unsigned)(t * 64 + lane);
            }
            base += (unsigned)__popcll(mask);
        }
    }
    __threadfence_block();
    const int m = (int)base;

    int* out = nbr + ((size_t)b * NPTS + i) * KNN;
    float ax = 0.f, ay = 0.f, az = 0.f;               // fused position sum

    if (m <= CAP) {
        // one LDS read per lane; rank via readlane loop (u64s are distinct)
        unsigned long long c0 = (lane < m) ? cand[w][lane] : ~0ULL;
        unsigned c0lo = (unsigned)c0, c0hi = (unsigned)(c0 >> 32);
        int r0 = 0;
        #pragma unroll 1
        for (int jj = 0; jj < m; ++jj) {
            unsigned shi = (unsigned)__builtin_amdgcn_readlane((int)c0hi, jj);
            unsigned slo = (unsigned)__builtin_amdgcn_readlane((int)c0lo, jj);
            r0 += (shi < c0hi) || (shi == c0hi && slo < c0lo);
        }
        if (lane < m && r0 < KNN) {
            unsigned j = c0lo;
            out[r0] = (int)j;
            float4 q = pts[j]; ax += q.x; ay += q.y; az += q.z;
        }
    } else {
        // exact fallback (never taken w/ random data; correctness only)
        unsigned T = 0;
        #pragma unroll 1
        for (int bit = 31; bit >= 0; --bit) {
            unsigned trial = T | (1u << bit);
            int cnt = 0;
            #pragma unroll
            for (int t = 0; t < 32; ++t) cnt += (key[t] < trial);
            #pragma unroll
            for (int off = 32; off; off >>= 1)
                cnt += __shfl_xor(cnt, off, 64);
            if (cnt < KNN) T = trial;
        }
        unsigned bs = 0;
        #pragma unroll 1
        for (int t = 0; t < 32; ++t) {
            bool p1 = key[t] < T;
            unsigned long long mask = __ballot(p1);
            if (mask) {
                unsigned prefix = __builtin_amdgcn_mbcnt_hi(
                    (unsigned)(mask >> 32),
                    __builtin_amdgcn_mbcnt_lo((unsigned)mask, 0));
                if (p1) {
                    out[bs + prefix] = t * 64 + lane;
                    float4 q = pts[t * 64 + lane];
                    ax += q.x; ay += q.y; az += q.z;
                }
                bs += (unsigned)__popcll(mask);
            }
        }
        #pragma unroll 1
        for (int t = 0; t < 32 && bs < KNN; ++t) {
            bool p2 = key[t] == T;
            unsigned long long mask = __ballot(p2);
            if (mask) {
                unsigned prefix = __builtin_amdgcn_mbcnt_hi(
                    (unsigned)(mask >> 32),
                    __builtin_amdgcn_mbcnt_lo((unsigned)mask, 0));
                unsigned pos = bs + prefix;
                if (p2 && pos < KNN) {
                    out[pos] = t * 64 + lane;
                    float4 q = pts[t * 64 + lane];
                    ax += q.x; ay += q.y; az += q.z;
                }
                bs += (unsigned)__popcll(mask);
            }
        }
    }

    #pragma unroll
    for (int off = 32; off; off >>= 1) {
        ax += __shfl_xor(ax, off, 64);
        ay += __shfl_xor(ay, off, 64);
        az += __shfl_xor(az, off, 64);
    }

    // ---- fused layer 1 -> LDS stage -> chunked-T write --------------------
    #pragma unroll
    for (int hh = 0; hh < 2; ++hh) {
        int h = lane + hh * 64;
        float acc = b1[h];
        acc += W1r[h * 3 + 0] * ax + W1r[h * 3 + 1] * ay + W1r[h * 3 + 2] * az;
        acc += W1s[h * 3 + 0] * pi.x + W1s[h * 3 + 1] * pi.y + W1s[h * 3 + 2] * pi.z;
        xst[w][h] = f2bf(fmaxf(acc, 0.f));
    }
    __syncthreads();
    if (threadIdx.x < RPB * 16) {                 // 128 tasks x 16 B
        int pt = threadIdx.x & 7, cc = threadIdx.x >> 3;
        uint4 vv = *(const uint4*)&xst[pt][cc * 8];
        *(uint4*)&x1T[((size_t)cc * NPOINTS + (size_t)b * NPTS + rblk * RPB + pt) * 8] = vv;
    }
}

// ---------------------------------------------------------------------------
// Weight conversion: 4 x [128x128] f32 -> bf16 chunked-T (wT[cc][h][8]).
// ---------------------------------------------------------------------------
__global__ __launch_bounds__(256) void wcvt_kernel(
    const float* __restrict__ a, const float* __restrict__ b,
    const float* __restrict__ c, const float* __restrict__ d,
    unsigned short* __restrict__ out)
{
    int g = blockIdx.x * 256 + threadIdx.x;       // < 65536
    int m = g >> 14;
    int e = g & 16383;
    int r = e >> 7, cch = e & 127;
    const float* s = (m == 0) ? a : (m == 1) ? b : (m == 2) ? c : d;
    out[m * 16384 + ((cch >> 3) * 128 + r) * 8 + (cch & 7)] = f2bf(s[e]);
}

// ---------------------------------------------------------------------------
// Gather via LDS: block = (batch, chunk). Stages the whole batch's 8-channel
// slice (2048 x 16 B, contiguous read) into LDS at 24 B stride, then each
// thread gathers 16 neighbor slices from LDS (b64 pairs) and writes the agg
// slice chunked-T. Cuts per-conv global gather traffic 134 MB -> ~10 MB.
// Grid index bi: batch = bi & 15 (XCD = bi % 8 heuristic -> nbr L2 locality).
// ---------------------------------------------------------------------------
__global__ __launch_bounds__(1024) void gather_kernel(
    const unsigned short* __restrict__ xT, const int* __restrict__ nbr,
    unsigned short* __restrict__ aggT)
{
    __shared__ __align__(16) unsigned short rows[NPTS * 12];   // 48 KB, 24B/row
    const int b = blockIdx.x & 15;
    const int cc = blockIdx.x >> 4;
    const unsigned short* src = xT + ((size_t)cc * NPOINTS + (size_t)b * NPTS) * 8;

    #pragma unroll
    for (int rr = 0; rr < 2; ++rr) {
        int t = rr * 1024 + threadIdx.x;
        uint4 vv = *(const uint4*)(src + t * 8);
        *(uint2*)&rows[t * 12] = make_uint2(vv.x, vv.y);
        *(uint2*)&rows[t * 12 + 4] = make_uint2(vv.z, vv.w);
    }
    __syncthreads();

    const int* nb = nbr + (size_t)b * NPTS * KNN;
    unsigned short* dst = aggT + ((size_t)cc * NPOINTS + (size_t)b * NPTS) * 8;

    #pragma unroll
    for (int rr = 0; rr < 2; ++rr) {
        int pt = rr * 1024 + threadIdx.x;
        const int4* nr4 = (const int4*)(nb + (size_t)pt * KNN);
        int4 n0 = nr4[0], n1 = nr4[1], n2 = nr4[2], n3 = nr4[3];
        int idx[16] = {n0.x, n0.y, n0.z, n0.w, n1.x, n1.y, n1.z, n1.w,
                       n2.x, n2.y, n2.z, n2.w, n3.x, n3.y, n3.z, n3.w};
        float s[8] = {0, 0, 0, 0, 0, 0, 0, 0};
        #pragma unroll
        for (int t = 0; t < KNN; ++t) {
            int j = idx[t];
            uint2 va = *(const uint2*)&rows[j * 12];
            uint2 vb = *(const uint2*)&rows[j * 12 + 4];
            s[0] += bflo(va.x); s[1] += bfhi(va.x);
            s[2] += bflo(va.y); s[3] += bfhi(va.y);
            s[4] += bflo(vb.x); s[5] += bfhi(vb.x);
            s[6] += bflo(vb.y); s[7] += bfhi(vb.y);
        }
        uint4 ov;
        ov.x = (unsigned)f2bf(s[0]) | ((unsigned)f2bf(s[1]) << 16);
        ov.y = (unsigned)f2bf(s[2]) | ((unsigned)f2bf(s[3]) << 16);
        ov.z = (unsigned)f2bf(s[4]) | ((unsigned)f2bf(s[5]) << 16);
        ov.w = (unsigned)f2bf(s[6]) | ((unsigned)f2bf(s[7]) << 16);
        *(uint4*)(dst + (size_t)pt * 8) = ov;
    }
}

// ---------------------------------------------------------------------------
// Pure GEMM conv: out[p][h] = Wr@agg_p + Ws@x_p + b (+relu). All operands
// chunked-T -> every read 256 B coalesced; zero random access.
// 512 thr, 64 pt x 128 h, wave tile 32x32 (2x2 MFMA). LDS-staged epilogue:
// conv1 -> x2 chunked-T bf16; conv2 -> row-major f32 out.
// D layout [verified R5+]: point = quad*4+reg, h = lane&15.
// ---------------------------------------------------------------------------
template <bool RELU, bool OUT_CHUNKED>
__global__ __launch_bounds__(512) void convmm_kernel(
    const unsigned short* __restrict__ aggT, const unsigned short* __restrict__ xT,
    const unsigned short* __restrict__ wTr, const unsigned short* __restrict__ wTs,
    const float* __restrict__ bias, void* __restrict__ outv)
{
    // union: bf16 tile [64][136] (17.4 KB) / f32 tile [64][132] (33.8 KB)
    __shared__ __align__(16) char smem[64 * 132 * 4];
    unsigned short (*obf)[136] = (unsigned short (*)[136])smem;
    float (*of32)[132] = (float (*)[132])smem;

    const int p0 = blockIdx.x * 64;
    const int wv = threadIdx.x >> 6;
    const int lane = threadIdx.x & 63;
    const int ptw = (wv & 1) * 32;                // 0 / 32
    const int h0w = (wv >> 1) * 32;               // 0 / 32 / 64 / 96
    const int row = lane & 15;
    const int quad = lane >> 4;

    f32x4 acc[2][2];
    #pragma unroll
    for (int i = 0; i < 2; ++i)
        #pragma unroll
        for (int n = 0; n < 2; ++n) acc[i][n] = (f32x4){0, 0, 0, 0};

    // agg @ Wr^T
    #pragma unroll
    for (int kc = 0; kc < 4; ++kc) {
        const int pl = quad + 4 * kc;             // chunk plane = k/8
        bf16x8 a0 = *(const bf16x8*)(aggT + ((size_t)pl * NPOINTS + p0 + ptw + row) * 8);
        bf16x8 a1 = *(const bf16x8*)(aggT + ((size_t)pl * NPOINTS + p0 + ptw + 16 + row) * 8);
        #pragma unroll
        for (int n = 0; n < 2; ++n) {
            bf16x8 bb = *(const bf16x8*)(wTr + ((size_t)pl * HID + h0w + n * 16 + row) * 8);
            acc[0][n] = __builtin_amdgcn_mfma_f32_16x16x32_bf16(a0, bb, acc[0][n], 0, 0, 0);
            acc[1][n] = __builtin_amdgcn_mfma_f32_16x16x32_bf16(a1, bb, acc[1][n], 0, 0, 0);
        }
    }
    // x @ Ws^T
    #pragma unroll
    for (int kc = 0; kc < 4; ++kc) {
        const int pl = quad + 4 * kc;
        bf16x8 a0 = *(const bf16x8*)(xT + ((size_t)pl * NPOINTS + p0 + ptw + row) * 8);
        bf16x8 a1 = *(const bf16x8*)(xT + ((size_t)pl * NPOINTS + p0 + ptw + 16 + row) * 8);
        #pragma unroll
        for (int n = 0; n < 2; ++n) {
            bf16x8 bb = *(const bf16x8*)(wTs + ((size_t)pl * HID + h0w + n * 16 + row) * 8);
            acc[0][n] = __builtin_amdgcn_mfma_f32_16x16x32_bf16(a0, bb, acc[0][n], 0, 0, 0);
            acc[1][n] = __builtin_amdgcn_mfma_f32_16x16x32_bf16(a1, bb, acc[1][n], 0, 0, 0);
        }
    }

    // ---- epilogue: bias/relu -> LDS tile -> coalesced stores --------------
    #pragma unroll
    for (int n = 0; n < 2; ++n) {
        float bh = bias[h0w + n * 16 + row];
        #pragma unroll
        for (int i = 0; i < 2; ++i) {
            #pragma unroll
            for (int r = 0; r < 4; ++r) {
                int pt = ptw + i * 16 + quad * 4 + r;     // 0..63 in tile
                int hh = h0w + n * 16 + row;              // 0..127
                float vv = acc[i][n][r] + bh;
                if (RELU) vv = fmaxf(vv, 0.f);
                if (OUT_CHUNKED) obf[pt][hh] = f2bf(vv);
                else             of32[pt][hh] = vv;
            }
        }
    }
    __syncthreads();

    if (OUT_CHUNKED) {
        unsigned short* o = (unsigned short*)outv;        // chunked-T bf16
        #pragma unroll
        for (int q = 0; q < 2; ++q) {
            int task = q * 512 + threadIdx.x;     // 1024 = 64 pts x 16 cc
            int pt = task & 63, cc = task >> 6;
            *(uint4*)(o + ((size_t)cc * NPOINTS + p0 + pt) * 8) =
                *(const uint4*)&obf[pt][cc * 8];
        }
    } else {
        float* o = (float*)outv;                          // row-major f32
        #pragma unroll
        for (int q = 0; q < 4; ++q) {
            int task = q * 512 + threadIdx.x;     // 2048 = 64 rows x 32 chunks
            int rr = task >> 5, ch = task & 31;
            *(float4*)(o + (size_t)(p0 + rr) * HID + ch * 4) =
                *(const float4*)&of32[rr][ch * 4];
        }
    }
}

// ---------------------------------------------------------------------------
extern "C" void kernel_launch(void* const* d_in, const int* in_sizes, int n_in,
                              void* d_out, int out_size, void* d_ws, size_t ws_size,
                              hipStream_t stream)
{
    const float* pc  = (const float*)d_in[0];
    const float* W1r = (const float*)d_in[1];
    const float* b1  = (const float*)d_in[2];
    const float* W1s = (const float*)d_in[3];
    const float* W2r = (const float*)d_in[4];
    const float* b2  = (const float*)d_in[5];
    const float* W2s = (const float*)d_in[6];
    const float* W3r = (const float*)d_in[7];
    const float* b3  = (const float*)d_in[8];
    const float* W3s = (const float*)d_in[9];
    float* out = (float*)d_out;

    char* ws = (char*)d_ws;
    const size_t MB = 1024 * 1024;
    const size_t XSZ = (size_t)NPOINTS * HID * 2;                // 8.39 MB
    int*            nbr  = (int*)ws;                             // 2 MB
    unsigned short* x1T  = (unsigned short*)(ws + 2 * MB);
    unsigned short* x2T  = (unsigned short*)(ws + 2 * MB + XSZ);
    unsigned short* aggT = (unsigned short*)(ws + 2 * MB + 2 * XSZ);
    unsigned short* wT   = (unsigned short*)(ws + 2 * MB + 3 * XSZ);
    unsigned short* w2rT = wT;
    unsigned short* w2sT = wT + 16384;
    unsigned short* w3rT = wT + 32768;
    unsigned short* w3sT = wT + 49152;

    wcvt_kernel<<<256, 256, 0, stream>>>(W2r, W2s, W3r, W3s, wT);
    knn_kernel<<<NPOINTS / RPB, 512, 0, stream>>>(pc, nbr, W1r, b1, W1s, x1T);

    gather_kernel<<<256, 1024, 0, stream>>>(x1T, nbr, aggT);
    convmm_kernel<true, true><<<NPOINTS / 64, 512, 0, stream>>>(
        aggT, x1T, w2rT, w2sT, b2, x2T);

    gather_kernel<<<256, 1024, 0, stream>>>(x2T, nbr, aggT);
    convmm_kernel<false, false><<<NPOINTS / 64, 512, 0, stream>>>(
        aggT, x2T, w3rT, w3sT, b3, out);
}